// Round 4
// baseline (119.432 us; speedup 1.0000x reference)
//
#include <hip/hip_runtime.h>
#include <hip/hip_cooperative_groups.h>
#include <math.h>

namespace cg = cooperative_groups;

#define LL 50
#define DD 50
#define RR 3
#define CC 10

#define FUSED_BLOCKS 1024
#define FUSED_THREADS 256
#define FUSED_WAVES (FUSED_BLOCKS * FUSED_THREADS / 64)   // 4096

// ---------------- Fused single-launch kernel (cooperative) ----------------
__global__ __launch_bounds__(FUSED_THREADS, 4) void fused_all_kernel(
    const int*    __restrict__ x,          // [B, L]
    const float*  __restrict__ emb_mask,   // [B, L]
    const int*    __restrict__ combo_idx,  // [B, C, R]
    const float*  __restrict__ emb_table,  // [VOCAB, D]
    const float*  __restrict__ W,          // [150]
    const float*  __restrict__ bvec,       // [1]
    float4*       __restrict__ dtab,       // [VOCAB] scratch
    float*        __restrict__ out,        // [B]
    int B, int vocab)
{
    const int tid = blockIdx.x * FUSED_THREADS + threadIdx.x;

    // ---- Phase 1: dtab[v] = (row_v . w0, row_v . w1, row_v . w2, 0) ----
    // One row per thread; a wave covers 64 consecutive rows (12.8 KB) which
    // the L1 amortizes across the 25-iteration loop.
    for (int v = tid; v < vocab; v += FUSED_BLOCKS * FUSED_THREADS) {
        const float* p = emb_table + (size_t)v * DD;   // 200B rows, 8B aligned
        float d0 = 0.f, d1 = 0.f, d2 = 0.f;
        #pragma unroll
        for (int j = 0; j < DD / 2; ++j) {
            float2 e = *reinterpret_cast<const float2*>(p + 2 * j);
            // W index is wave-uniform -> scalar loads
            d0 = fmaf(e.x, W[          2 * j], fmaf(e.y, W[          2 * j + 1], d0));
            d1 = fmaf(e.x, W[    DD  + 2 * j], fmaf(e.y, W[    DD  + 2 * j + 1], d1));
            d2 = fmaf(e.x, W[2 * DD  + 2 * j], fmaf(e.y, W[2 * DD  + 2 * j + 1], d2));
        }
        dtab[v] = make_float4(d0, d1, d2, 0.f);
    }

    cg::this_grid().sync();

    // ---- Phase 2: one wave per sample, 8 samples per wave ----
    const int  lane = threadIdx.x & 63;
    const int  gw   = tid >> 6;
    const float bias = bvec[0];

    for (int b = gw; b < B; b += FUSED_WAVES) {
        float d0 = 0.f, d1 = 0.f, d2 = 0.f;
        if (lane < LL) {
            int   row = x[b * LL + lane];
            float m   = emb_mask[b * LL + lane];
            float4 d  = dtab[row];            // 16B gather, 1.6MB L2-resident
            d0 = d.x * m; d1 = d.y * m; d2 = d.z * m;
        }
        int ci = 0;
        if (lane < CC * RR) ci = combo_idx[b * (CC * RR) + lane];
        int i0 = __shfl(ci, 3 * lane    ) & 63;
        int i1 = __shfl(ci, 3 * lane + 1) & 63;
        int i2 = __shfl(ci, 3 * lane + 2) & 63;

        float sacc = __shfl(d0, i0) + __shfl(d1, i1) + __shfl(d2, i2) + bias;
        float v = (lane < CC) ? 1.0f / (1.0f + __expf(-sacc)) : 0.f;

        v += __shfl_down(v, 8);
        v += __shfl_down(v, 4);
        v += __shfl_down(v, 2);
        v += __shfl_down(v, 1);
        if (lane == 0) out[b] = v;
    }
}

// ---------------- Fallback 2-kernel path ----------------
__global__ __launch_bounds__(256) void precompute_dots_kernel(
    const float* __restrict__ emb_table, const float* __restrict__ W,
    float4* __restrict__ dtab, int vocab)
{
    int v = blockIdx.x * 256 + threadIdx.x;
    if (v >= vocab) return;
    const float* p = emb_table + (size_t)v * DD;
    float d0 = 0.f, d1 = 0.f, d2 = 0.f;
    #pragma unroll
    for (int j = 0; j < DD / 2; ++j) {
        float2 e = *reinterpret_cast<const float2*>(p + 2 * j);
        d0 = fmaf(e.x, W[          2 * j], fmaf(e.y, W[          2 * j + 1], d0));
        d1 = fmaf(e.x, W[    DD  + 2 * j], fmaf(e.y, W[    DD  + 2 * j + 1], d1));
        d2 = fmaf(e.x, W[2 * DD  + 2 * j], fmaf(e.y, W[2 * DD  + 2 * j + 1], d2));
    }
    dtab[v] = make_float4(d0, d1, d2, 0.f);
}

__global__ __launch_bounds__(256) void fused_combo_kernel(
    const int* __restrict__ x, const float* __restrict__ emb_mask,
    const int* __restrict__ combo_idx, const float4* __restrict__ dtab,
    const float* __restrict__ bvec, float* __restrict__ out, int B)
{
    const int tid  = threadIdx.x;
    const int w    = tid >> 6;
    const int lane = tid & 63;
    const int b    = blockIdx.x * 4 + w;
    if (b >= B) return;

    float d0 = 0.f, d1 = 0.f, d2 = 0.f;
    if (lane < LL) {
        int   row = x[b * LL + lane];
        float m   = emb_mask[b * LL + lane];
        float4 d  = dtab[row];
        d0 = d.x * m; d1 = d.y * m; d2 = d.z * m;
    }
    int ci = 0;
    if (lane < CC * RR) ci = combo_idx[b * (CC * RR) + lane];
    int i0 = __shfl(ci, 3 * lane    ) & 63;
    int i1 = __shfl(ci, 3 * lane + 1) & 63;
    int i2 = __shfl(ci, 3 * lane + 2) & 63;

    float sacc = __shfl(d0, i0) + __shfl(d1, i1) + __shfl(d2, i2) + bvec[0];
    float v = (lane < CC) ? 1.0f / (1.0f + __expf(-sacc)) : 0.f;
    v += __shfl_down(v, 8);
    v += __shfl_down(v, 4);
    v += __shfl_down(v, 2);
    v += __shfl_down(v, 1);
    if (lane == 0) out[b] = v;
}

extern "C" void kernel_launch(void* const* d_in, const int* in_sizes, int n_in,
                              void* d_out, int out_size, void* d_ws, size_t ws_size,
                              hipStream_t stream) {
    const int*   x         = (const int*)d_in[0];
    const float* emb_mask  = (const float*)d_in[1];
    const int*   combo_idx = (const int*)d_in[2];
    // d_in[3] = step (unused)
    const float* emb_table = (const float*)d_in[4];
    const float* W         = (const float*)d_in[5];
    const float* bvec      = (const float*)d_in[6];
    float*       out       = (float*)d_out;

    int B     = out_size;             // OUT == 1
    int vocab = in_sizes[4] / DD;     // emb_table is [VOCAB, D]

    float4* dtab = (float4*)d_ws;     // 16 * VOCAB = 1.6 MB scratch

    void* args[] = { (void*)&x, (void*)&emb_mask, (void*)&combo_idx,
                     (void*)&emb_table, (void*)&W, (void*)&bvec,
                     (void*)&dtab, (void*)&out, (void*)&B, (void*)&vocab };

    hipError_t err = hipLaunchCooperativeKernel(
        (const void*)fused_all_kernel, dim3(FUSED_BLOCKS), dim3(FUSED_THREADS),
        args, 0, stream);

    if (err != hipSuccess) {
        // Fallback: classic two-launch pipeline.
        precompute_dots_kernel<<<(vocab + 255) / 256, 256, 0, stream>>>(
            emb_table, W, dtab, vocab);
        fused_combo_kernel<<<(B + 3) / 4, 256, 0, stream>>>(
            x, emb_mask, combo_idx, dtab, bvec, out, B);
    }
}

// Round 5
// 23.231 us; speedup vs baseline: 5.1411x; 5.1411x over previous
//
#include <hip/hip_runtime.h>
#include <math.h>

#define LL 50
#define DD 50
#define RR 3
#define CC 10

// ---------------- Kernel 1: dtab[v] = (row_v.w0, row_v.w1, row_v.w2, 0) ----
// 4 lanes per vocab row -> 400k threads (~24 waves/CU) for latency hiding.
// Lane q of a row handles float2-pairs [s, s+c): q0:0..6, q1:7..12, q2:13..18,
// q3:19..24 (elems 14/12/12/12 = 50). W is staged in LDS (lane-varying index).
__global__ __launch_bounds__(256) void precompute_dots_kernel(
    const float* __restrict__ emb_table,  // [VOCAB, D]
    const float* __restrict__ W,          // [150]
    float4*      __restrict__ dtab,       // [VOCAB]
    int vocab)
{
    __shared__ float sW[RR * DD];
    if (threadIdx.x < RR * DD) sW[threadIdx.x] = W[threadIdx.x];
    __syncthreads();

    const int tid = blockIdx.x * 256 + threadIdx.x;
    const int r   = tid >> 2;          // row
    const int q   = tid & 3;           // quarter
    if (r >= vocab) return;            // whole 4-lane group exits together

    const float2* p = reinterpret_cast<const float2*>(emb_table + (size_t)r * DD);
    const int s = 6 * q + (q > 0 ? 1 : 0);   // 0,7,13,19
    const int c = (q == 0) ? 7 : 6;

    float d0 = 0.f, d1 = 0.f, d2 = 0.f;
    #pragma unroll
    for (int k = 0; k < 7; ++k) {
        if (k < c) {
            float2 e = p[s + k];
            int j = 2 * (s + k);
            d0 = fmaf(e.x, sW[          j], fmaf(e.y, sW[          j + 1], d0));
            d1 = fmaf(e.x, sW[    DD  + j], fmaf(e.y, sW[    DD  + j + 1], d1));
            d2 = fmaf(e.x, sW[2 * DD  + j], fmaf(e.y, sW[2 * DD  + j + 1], d2));
        }
    }
    // Reduce across the 4-lane group.
    d0 += __shfl_xor(d0, 1); d0 += __shfl_xor(d0, 2);
    d1 += __shfl_xor(d1, 1); d1 += __shfl_xor(d1, 2);
    d2 += __shfl_xor(d2, 1); d2 += __shfl_xor(d2, 2);
    if (q == 0) dtab[r] = make_float4(d0, d1, d2, 0.f);
}

// ---------------- Kernel 2: one wave per sample, shuffle-only ----------------
__global__ __launch_bounds__(256) void fused_combo_kernel(
    const int*    __restrict__ x,          // [B, L]
    const float*  __restrict__ emb_mask,   // [B, L]
    const int*    __restrict__ combo_idx,  // [B, C, R], values in [0, L)
    const float4* __restrict__ dtab,       // [VOCAB]
    const float*  __restrict__ bvec,       // [1]
    float*        __restrict__ out,        // [B]
    int B)
{
    const int tid  = threadIdx.x;
    const int w    = tid >> 6;
    const int lane = tid & 63;
    const int b    = blockIdx.x * 4 + w;
    if (b >= B) return;                    // wave-uniform

    // Combo indices: lanes 0..29.
    int ci = 0;
    if (lane < CC * RR) ci = combo_idx[b * (CC * RR) + lane];

    // Used-position mask (which of the 50 lanes' dtab gathers are needed).
    unsigned long long um = (lane < CC * RR) ? (1ull << ci) : 0ull;
    um |= __shfl_xor(um, 32);
    um |= __shfl_xor(um, 16);
    um |= __shfl_xor(um,  8);
    um |= __shfl_xor(um,  4);
    um |= __shfl_xor(um,  2);
    um |= __shfl_xor(um,  1);
    const bool used = (lane < LL) && ((um >> lane) & 1ull);

    // Coalesced x/mask loads for lanes <50; dtab gather only for used lanes.
    float d0 = 0.f, d1 = 0.f, d2 = 0.f;
    if (lane < LL) {
        int   row = x[b * LL + lane];
        float m   = emb_mask[b * LL + lane];
        if (used) {
            float4 d = dtab[row];          // 16B gather, ~23 lanes active
            d0 = d.x * m; d1 = d.y * m; d2 = d.z * m;
        }
    }

    // Redistribute: lane c (<10) collects its 3 combo indices, gathers d-values.
    int i0 = __shfl(ci, 3 * lane    ) & 63;
    int i1 = __shfl(ci, 3 * lane + 1) & 63;
    int i2 = __shfl(ci, 3 * lane + 2) & 63;

    float sacc = __shfl(d0, i0) + __shfl(d1, i1) + __shfl(d2, i2) + bvec[0];
    float v = (lane < CC) ? 1.0f / (1.0f + __expf(-sacc)) : 0.f;

    v += __shfl_down(v, 8);
    v += __shfl_down(v, 4);
    v += __shfl_down(v, 2);
    v += __shfl_down(v, 1);
    if (lane == 0) out[b] = v;
}

extern "C" void kernel_launch(void* const* d_in, const int* in_sizes, int n_in,
                              void* d_out, int out_size, void* d_ws, size_t ws_size,
                              hipStream_t stream) {
    const int*   x         = (const int*)d_in[0];
    const float* emb_mask  = (const float*)d_in[1];
    const int*   combo_idx = (const int*)d_in[2];
    // d_in[3] = step (unused)
    const float* emb_table = (const float*)d_in[4];
    const float* W         = (const float*)d_in[5];
    const float* bvec      = (const float*)d_in[6];
    float*       out       = (float*)d_out;

    const int B     = out_size;            // OUT == 1
    const int vocab = in_sizes[4] / DD;    // emb_table is [VOCAB, D]

    float4* dtab = (float4*)d_ws;          // 16 * VOCAB = 1.6 MB scratch

    const int pc_threads = 4 * vocab;
    precompute_dots_kernel<<<(pc_threads + 255) / 256, 256, 0, stream>>>(
        emb_table, W, dtab, vocab);

    fused_combo_kernel<<<(B + 3) / 4, 256, 0, stream>>>(
        x, emb_mask, combo_idx, dtab, bvec, out, B);
}

// Round 6
// 19.197 us; speedup vs baseline: 6.2212x; 1.2101x over previous
//
#include <hip/hip_runtime.h>
#include <math.h>

#define LL 50
#define DD 50
#define RR 3
#define CC 10

// ---------------- Kernel 1: dtab[v] = (row_v.w0, row_v.w1, row_v.w2, 0) ----
// 4 lanes per vocab row (~24 waves/CU). Lane q handles float2-pairs
// [s, s+c): q0:0..6, q1:7..12, q2:13..18, q3:19..24. W staged in LDS.
__global__ __launch_bounds__(256) void precompute_dots_kernel(
    const float* __restrict__ emb_table,  // [VOCAB, D]
    const float* __restrict__ W,          // [150]
    float4*      __restrict__ dtab,       // [VOCAB]
    int vocab)
{
    __shared__ float sW[RR * DD];
    if (threadIdx.x < RR * DD) sW[threadIdx.x] = W[threadIdx.x];
    __syncthreads();

    const int tid = blockIdx.x * 256 + threadIdx.x;
    const int r   = tid >> 2;          // row
    const int q   = tid & 3;           // quarter
    if (r >= vocab) return;            // whole 4-lane group exits together

    const float2* p = reinterpret_cast<const float2*>(emb_table + (size_t)r * DD);
    const int s = 6 * q + (q > 0 ? 1 : 0);   // 0,7,13,19
    const int c = (q == 0) ? 7 : 6;

    float d0 = 0.f, d1 = 0.f, d2 = 0.f;
    #pragma unroll
    for (int k = 0; k < 7; ++k) {
        if (k < c) {
            float2 e = p[s + k];
            int j = 2 * (s + k);
            d0 = fmaf(e.x, sW[          j], fmaf(e.y, sW[          j + 1], d0));
            d1 = fmaf(e.x, sW[    DD  + j], fmaf(e.y, sW[    DD  + j + 1], d1));
            d2 = fmaf(e.x, sW[2 * DD  + j], fmaf(e.y, sW[2 * DD  + j + 1], d2));
        }
    }
    d0 += __shfl_xor(d0, 1); d0 += __shfl_xor(d0, 2);
    d1 += __shfl_xor(d1, 1); d1 += __shfl_xor(d1, 2);
    d2 += __shfl_xor(d2, 1); d2 += __shfl_xor(d2, 2);
    if (q == 0) dtab[r] = make_float4(d0, d1, d2, 0.f);
}

// ---------------- Kernel 2: thread-per-combo, 4 samples per wave ----------
// Lane layout: s = lane>>4 (sample within wave), c = lane&15 (combo, <10
// active). Chain: combo_idx -> x/mask gather (L1, 800B/wave) -> dtab
// component gather (L2-resident 1.6MB). One 16-lane shfl tree per sample.
__global__ __launch_bounds__(256) void combo_eval_kernel(
    const int*    __restrict__ x,          // [B, L]
    const float*  __restrict__ emb_mask,   // [B, L]
    const int*    __restrict__ combo_idx,  // [B, C, R]
    const float*  __restrict__ dtabf,      // [VOCAB*4]: component r at 4*row+r
    const float*  __restrict__ bvec,       // [1]
    float*        __restrict__ out,        // [B]
    int B)
{
    const int lane = threadIdx.x & 63;
    const int gw   = blockIdx.x * 4 + (threadIdx.x >> 6);
    const int s    = lane >> 4;
    const int c    = lane & 15;
    const int b    = gw * 4 + s;

    float v = 0.f;
    if (b < B && c < CC) {
        const size_t cb = ((size_t)b * CC + c) * RR;
        int i0 = combo_idx[cb + 0];
        int i1 = combo_idx[cb + 1];
        int i2 = combo_idx[cb + 2];
        const int*   xr = x        + b * LL;
        const float* mr = emb_mask + b * LL;
        int   r0 = xr[i0], r1 = xr[i1], r2 = xr[i2];
        float m0 = mr[i0], m1 = mr[i1], m2 = mr[i2];
        float sacc = dtabf[4 * r0 + 0] * m0
                   + dtabf[4 * r1 + 1] * m1
                   + dtabf[4 * r2 + 2] * m2
                   + bvec[0];
        v = 1.0f / (1.0f + __expf(-sacc));
    }
    // Sum the 16-lane group (lanes c>=10 carry zeros; tree stays clean).
    v += __shfl_down(v, 8);
    v += __shfl_down(v, 4);
    v += __shfl_down(v, 2);
    v += __shfl_down(v, 1);
    if (c == 0 && b < B) out[b] = v;
}

extern "C" void kernel_launch(void* const* d_in, const int* in_sizes, int n_in,
                              void* d_out, int out_size, void* d_ws, size_t ws_size,
                              hipStream_t stream) {
    const int*   x         = (const int*)d_in[0];
    const float* emb_mask  = (const float*)d_in[1];
    const int*   combo_idx = (const int*)d_in[2];
    // d_in[3] = step (unused)
    const float* emb_table = (const float*)d_in[4];
    const float* W         = (const float*)d_in[5];
    const float* bvec      = (const float*)d_in[6];
    float*       out       = (float*)d_out;

    const int B     = out_size;            // OUT == 1
    const int vocab = in_sizes[4] / DD;    // emb_table is [VOCAB, D]

    float4* dtab = (float4*)d_ws;          // 16 * VOCAB = 1.6 MB scratch

    const int pc_threads = 4 * vocab;
    precompute_dots_kernel<<<(pc_threads + 255) / 256, 256, 0, stream>>>(
        emb_table, W, dtab, vocab);

    const int samples_per_block = 16;      // 4 waves * 4 samples
    combo_eval_kernel<<<(B + samples_per_block - 1) / samples_per_block, 256, 0, stream>>>(
        x, emb_mask, combo_idx, (const float*)dtab, bvec, out, B);
}